// Round 17
// baseline (173.960 us; speedup 1.0000x reference)
//
#include <hip/hip_runtime.h>
#include <hip/hip_bf16.h>
#include <stdint.h>

typedef __attribute__((ext_vector_type(8))) short short8;
typedef __attribute__((ext_vector_type(4))) float f32x4;
typedef __attribute__((ext_vector_type(16))) float f32x16;
typedef __attribute__((ext_vector_type(4))) unsigned short us4;
typedef __attribute__((ext_vector_type(4))) unsigned int u32x4;

#define AS1 __attribute__((address_space(1)))
#define AS3 __attribute__((address_space(3)))

__device__ inline unsigned short f2bf(float f) {
    unsigned int u = __float_as_uint(f);
    u += 0x7FFFu + ((u >> 16) & 1u);
    return (unsigned short)(u >> 16);
}

// RNE pack of two fp32 into one u32 of 2x bf16 (bit-exact with f2bf; the HW
// v_cvt_pk_bf16_f32 is NOT round-to-nearest-even -> 3.4e-3 absmax in R16).
__device__ inline unsigned int pk_rne(float a, float b) {
    unsigned int ua = __float_as_uint(a), ub = __float_as_uint(b);
    ua += 0x7FFFu + ((ua >> 16) & 1u);
    ub += 0x7FFFu + ((ub >> 16) & 1u);
    return (ua >> 16) | (ub & 0xFFFF0000u);
}

__device__ inline unsigned int cvtpk(float lo, float hi) {
    unsigned int r;
    asm("v_cvt_pk_bf16_f32 %0, %1, %2" : "=v"(r) : "v"(lo), "v"(hi));
    return r;
}

__device__ inline void pl32swap(unsigned int& a, unsigned int& b) {
    asm volatile("v_permlane32_swap_b32 %0, %1" : "+v"(a), "+v"(b));
}

__device__ inline float fexp2(float x) {
#if __has_builtin(__builtin_amdgcn_exp2f)
    return __builtin_amdgcn_exp2f(x);
#else
    return exp2f(x);
#endif
}

#define VMW(N) asm volatile("s_waitcnt vmcnt(" #N ")" ::: "memory")
#define LGKW0() asm volatile("s_waitcnt lgkmcnt(0)" ::: "memory")
#define BARR() __builtin_amdgcn_s_barrier()

// ---------------- fp32 -> bf16 conversion for w_qkv, w_proj only ------------
__global__ void cvt_w(const float* __restrict__ wq, const float* __restrict__ wp,
                      unsigned short* __restrict__ wqb,
                      unsigned short* __restrict__ wpb) {
    const int Q4 = 442368;   // WQ/4 (WP/4 = 147456); total 589824 quads
    int i = blockIdx.x * blockDim.x + threadIdx.x;
    const float* src; unsigned short* dst; int j;
    if (i < Q4) { src = wq; dst = wqb; j = i; }
    else        { src = wp; dst = wpb; j = i - Q4; }
    float4 v = ((const float4*)src)[j];
    us4 o;
    o.x = f2bf(v.x); o.y = f2bf(v.y); o.z = f2bf(v.z); o.w = f2bf(v.w);
    ((us4*)dst)[j] = o;
}

// ============ QKV GEMM with fused x conversion (RNE) ========================
// C = x * w_qkv^T. A (x, fp32) is reg-staged: coalesced fp32 loads ->
// pk_rne (bit-exact round-to-nearest-even) -> swizzled ds_write_b128.
// B (w_qkv, bf16) uses global_load_lds. 128x128 tile, BK=64, 2-buffer.
// Per iter: vmcnt(8) [B(t) landed, A-regs(t+1) in flight] -> barrier ->
// ds_reads(t) -> vmcnt(0) [A-regs(t+1)] -> cvt + ds_write A(t+1) ->
// issue B(t+1), A-regs(t+2) -> MFMA -> lgkm(0) -> barrier.
// Epilogue: Q/K [B*H,N,D] bf16 (Q scaled 0.125*log2e), V transposed into
// Vt [B*H, D, N] with k-quad permutation (PV MFMA B-frag order).
#define BM 128
#define BN 128

__global__ __launch_bounds__(256)
void qkv_gemm(const float* __restrict__ X,
              const unsigned short* __restrict__ Bm,
              unsigned short* __restrict__ Qo, unsigned short* __restrict__ Ko,
              unsigned short* __restrict__ Vto)
{
    __shared__ __align__(16) unsigned short As[2][BM * 64];
    __shared__ __align__(16) unsigned short Bs[2][BM * 64];
    const int tid = threadIdx.x;
    const int wave = tid >> 6, lane = tid & 63;
    const int tr = blockIdx.x * BM;
    const int tc = blockIdx.y * BN;
    const int wm = wave >> 1, wn = wave & 1;
    const int K = 768;

    f32x4 acc[4][4] = {};

    // A reg-staging geometry: row ar = tid>>1 (0..127), half ah = tid&1
    const int ar = tid >> 1, ah = tid & 1;
    const float* xrow = X + (size_t)(tr + ar) * K + ah * 32;

    f32x4 areg[8];
    auto loadA = [&](int it) {
#pragma unroll
        for (int j = 0; j < 8; ++j)
            areg[j] = *(const f32x4*)(xrow + it * 64 + j * 4);
    };
    auto writeA = [&](int buf) {
#pragma unroll
        for (int j2 = 0; j2 < 4; ++j2) {
            u32x4 w;
            w.x = pk_rne(areg[2 * j2][0], areg[2 * j2][1]);
            w.y = pk_rne(areg[2 * j2][2], areg[2 * j2][3]);
            w.z = pk_rne(areg[2 * j2 + 1][0], areg[2 * j2 + 1][1]);
            w.w = pk_rne(areg[2 * j2 + 1][2], areg[2 * j2 + 1][3]);
            int cd = ah * 4 + j2;
            *(u32x4*)&As[buf][ar * 64 + ((cd ^ (ar & 7)) * 8)] = w;
        }
    };
    auto stageB = [&](int it, int buf) {
#pragma unroll
        for (int i = 0; i < 4; ++i) {
            int cid = i * 256 + tid;          // 0..1023 = r*8 + cd
            int r = cid >> 3, cd = cid & 7;
            int sc = cd ^ (r & 7);
            __builtin_amdgcn_global_load_lds(
                (const AS1 void*)(Bm + (size_t)(tc + r) * K + it * 64 + sc * 8),
                (AS3 void*)(&Bs[buf][(i * 256 + wave * 64) * 8]), 16, 0, 0);
        }
    };

    const int nIt = K / 64;                    // 12
    // prologue: A(0) regs -> LDS buf0; B(0) -> buf0; A(1) regs in flight
    loadA(0);                                  // 8 loads
    stageB(0, 0);                              // 4 loads (12 in flight)
    VMW(4);                                    // A(0) regs landed
    writeA(0);
    loadA(1);                                  // 8 in flight (+B0 maybe)
    LGKW0();                                   // A(0) writes done

    for (int it = 0; it < nIt; ++it) {
        const int b = it & 1, nb = b ^ 1;
        if (it + 1 < nIt) { VMW(8); }          // B(it) landed; Areg(it+1) flying
        else              { VMW(0); }
        BARR();                                // buf b fully visible

        short8 af[4][2], bfr[4][2];
#pragma unroll
        for (int mt = 0; mt < 4; ++mt)
#pragma unroll
            for (int kh = 0; kh < 2; ++kh) {
                int rr = wm * 64 + mt * 16 + (lane & 15);
                int c = kh * 4 + (lane >> 4);
                af[mt][kh] = *(const short8*)&As[b][rr * 64 + ((c ^ (rr & 7)) * 8)];
            }
#pragma unroll
        for (int nt = 0; nt < 4; ++nt)
#pragma unroll
            for (int kh = 0; kh < 2; ++kh) {
                int rr = wn * 64 + nt * 16 + (lane & 15);
                int c = kh * 4 + (lane >> 4);
                bfr[nt][kh] = *(const short8*)&Bs[b][rr * 64 + ((c ^ (rr & 7)) * 8)];
            }

        if (it + 1 < nIt) {
            VMW(0);                            // Areg(it+1) landed
            writeA(nb);                        // A(it+1) -> buf nb
            stageB(it + 1, nb);                // 4 gload_lds
            if (it + 2 < nIt) loadA(it + 2);   // 8 reg loads
        }

        __builtin_amdgcn_s_setprio(1);
#pragma unroll
        for (int kh = 0; kh < 2; ++kh)
#pragma unroll
            for (int mt = 0; mt < 4; ++mt)
#pragma unroll
                for (int nt = 0; nt < 4; ++nt)
                    acc[mt][nt] = __builtin_amdgcn_mfma_f32_16x16x32_bf16(af[mt][kh], bfr[nt][kh], acc[mt][nt], 0, 0, 0);
        __builtin_amdgcn_s_setprio(0);

        LGKW0();                               // A-writes (and reads) drained
        BARR();                                // safe to overwrite next iter
    }

    const float QSCALE = 0.18033688011112042f;  // 0.125 * log2(e)
#pragma unroll
    for (int mt = 0; mt < 4; ++mt) {
#pragma unroll
        for (int nt = 0; nt < 4; ++nt) {
            int col = tc + wn * 64 + nt * 16 + (lane & 15);
            int row0 = tr + wm * 64 + mt * 16 + (lane >> 4) * 4;
            int s = (col >= 1536) ? 2 : (col >= 768 ? 1 : 0);
            int rem = col - s * 768;
            int h = rem >> 6, d = rem & 63;
            int b = row0 >> 10, n0 = row0 & 1023;
            int bh = b * 12 + h;
            if (s == 2) {
                us4 pv;
#pragma unroll
                for (int r = 0; r < 4; ++r) pv[r] = f2bf(acc[mt][nt][r]);
                // k-quad permutation within each 16-group: [0-3][8-11][4-7][12-15]
                int qd = (n0 >> 2) & 3;
                int nst = n0 + ((qd == 1) ? 4 : (qd == 2) ? -4 : 0);
                *(us4*)&Vto[((size_t)bh * 64 + d) * 1024 + nst] = pv;
            } else {
                unsigned short* dst = (s == 0) ? Qo : Ko;
                float sc = (s == 0) ? QSCALE : 1.0f;
#pragma unroll
                for (int r = 0; r < 4; ++r)
                    dst[((size_t)bh * 1024 + n0 + r) * 64 + d] = f2bf(acc[mt][nt][r] * sc);
            }
        }
    }
}

// ---------------- proj GEMM (R12 structure: 128x128, BK=64, 2-buf vmcnt(8)) --
__global__ __launch_bounds__(256)
void proj_gemm(const unsigned short* __restrict__ A,
               const unsigned short* __restrict__ Bm,
               float* __restrict__ Co, const float* __restrict__ bias,
               int M, int N, int K)
{
    __shared__ __align__(16) unsigned short As[2][BM * 64];
    __shared__ __align__(16) unsigned short Bs[2][BM * 64];
    const int tid = threadIdx.x;
    const int wave = tid >> 6, lane = tid & 63;
    const int tr = blockIdx.x * BM;
    const int tc = blockIdx.y * BN;
    const int wm = wave >> 1, wn = wave & 1;

    f32x4 acc[4][4] = {};

    auto stage = [&](int it, int buf) {
#pragma unroll
        for (int i = 0; i < 4; ++i) {
            int cid = i * 256 + tid;
            int r = cid >> 3, cd = cid & 7;
            int sc = cd ^ (r & 7);
            __builtin_amdgcn_global_load_lds(
                (const AS1 void*)(A + (size_t)(tr + r) * K + it * 64 + sc * 8),
                (AS3 void*)(&As[buf][(i * 256 + wave * 64) * 8]), 16, 0, 0);
            __builtin_amdgcn_global_load_lds(
                (const AS1 void*)(Bm + (size_t)(tc + r) * K + it * 64 + sc * 8),
                (AS3 void*)(&Bs[buf][(i * 256 + wave * 64) * 8]), 16, 0, 0);
        }
    };

    const int nIt = K / 64;                    // 12
    stage(0, 0);

    for (int it = 0; it < nIt; ++it) {
        const int cur = it & 1;
        if (it + 1 < nIt) { stage(it + 1, cur ^ 1); VMW(8); }
        else              { VMW(0); }
        BARR();

#pragma unroll
        for (int kh = 0; kh < 2; ++kh) {
            short8 af[4], bfr[4];
#pragma unroll
            for (int mt = 0; mt < 4; ++mt) {
                int rr = wm * 64 + mt * 16 + (lane & 15);
                int c = kh * 4 + (lane >> 4);
                af[mt] = *(const short8*)&As[cur][rr * 64 + ((c ^ (rr & 7)) * 8)];
            }
#pragma unroll
            for (int nt = 0; nt < 4; ++nt) {
                int rr = wn * 64 + nt * 16 + (lane & 15);
                int c = kh * 4 + (lane >> 4);
                bfr[nt] = *(const short8*)&Bs[cur][rr * 64 + ((c ^ (rr & 7)) * 8)];
            }
#pragma unroll
            for (int mt = 0; mt < 4; ++mt)
#pragma unroll
                for (int nt = 0; nt < 4; ++nt)
                    acc[mt][nt] = __builtin_amdgcn_mfma_f32_16x16x32_bf16(af[mt], bfr[nt], acc[mt][nt], 0, 0, 0);
        }

        BARR();
    }

#pragma unroll
    for (int mt = 0; mt < 4; ++mt)
#pragma unroll
        for (int nt = 0; nt < 4; ++nt) {
            int col = tc + wn * 64 + nt * 16 + (lane & 15);
            int row0 = tr + wm * 64 + mt * 16 + (lane >> 4) * 4;
#pragma unroll
            for (int r = 0; r < 4; ++r)
                Co[(size_t)(row0 + r) * N + col] = acc[mt][nt][r] + bias[col];
        }
}

// ---------------- flash attention (32x32 swapped QK^T, static softmax) ------
// Byte-identical to R12 (passed): 1D grid 768, head-pinned XCD swizzle,
// 3-deep ring, ONE barrier/iter.
__global__ __launch_bounds__(256, 3)
void attn_kernel(const unsigned short* __restrict__ Q,
                 const unsigned short* __restrict__ Kg,
                 const unsigned short* __restrict__ Vt,
                 unsigned short* __restrict__ Og)
{
    __shared__ __align__(16) unsigned short KV[3][2][64 * 64];

    const int tid = threadIdx.x;
    const int wave = tid >> 6, lane = tid & 63;
    const int l31 = lane & 31, hi = lane >> 5;

    const int id = blockIdx.x;                 // 768 blocks
    const int swz = (id & 7) * 96 + (id >> 3);
    const int bh = swz >> 3, qb = swz & 7;

    const int b = bh / 12, h = bh % 12;
    const size_t baseK = (size_t)bh * 1024 * 64;
    const size_t baseV = (size_t)bh * 64 * 1024;
    const int q0 = qb * 128 + wave * 32;

    short8 qf[4];
#pragma unroll
    for (int ds = 0; ds < 4; ++ds)
        qf[ds] = *(const short8*)&Q[baseK + (size_t)(q0 + l31) * 64 + ds * 16 + hi * 8];

    f32x16 ot0 = {}, ot1 = {};
    float l = 0.f;

    auto stage = [&](int kt, int buf) {
        const unsigned short* gK = Kg + baseK + (size_t)kt * 64 * 64;
        const unsigned short* gV = Vt + baseV + kt * 64;
#pragma unroll
        for (int i = 0; i < 2; ++i) {
            int c = wave * 128 + i * 64 + lane;
            int r = c >> 3, cc = c & 7;
            int sw = (cc ^ (r & 7)) * 8;
            __builtin_amdgcn_global_load_lds(
                (const AS1 void*)(gK + r * 64 + sw),
                (AS3 void*)(&KV[buf][0][(wave * 128 + i * 64) * 8]), 16, 0, 0);
            __builtin_amdgcn_global_load_lds(
                (const AS1 void*)(gV + (size_t)r * 1024 + sw),
                (AS3 void*)(&KV[buf][1][(wave * 128 + i * 64) * 8]), 16, 0, 0);
        }
    };

    auto rfrag = [&](const unsigned short* s, int row, int cc) -> short8 {
        return *(const short8*)&s[(row * 8 + (cc ^ (row & 7))) * 8];
    };

    auto pack8 = [&](const f32x16& S, int r0) -> short8 {
        union { unsigned int u[4]; short8 s; } fr;
#pragma unroll
        for (int w = 0; w < 4; ++w)
            fr.u[w] = cvtpk(S[r0 + 2 * w], S[r0 + 2 * w + 1]);
        return fr.s;
    };

    stage(0, 0);
    stage(1, 1);
    int cb = 0, sb = 2;

    for (int kt = 0; kt < 16; ++kt) {
        if (kt < 15) { VMW(4); }
        else         { VMW(0); }
        BARR();
        if (kt < 14) stage(kt + 2, sb);

        f32x16 st0 = {}, st1 = {};
        __builtin_amdgcn_s_setprio(1);
#pragma unroll
        for (int ds = 0; ds < 4; ++ds) {
            short8 k0 = rfrag(KV[cb][0], l31, ds * 2 + hi);
            short8 k1 = rfrag(KV[cb][0], 32 + l31, ds * 2 + hi);
            st0 = __builtin_amdgcn_mfma_f32_32x32x16_bf16(k0, qf[ds], st0, 0, 0, 0);
            st1 = __builtin_amdgcn_mfma_f32_32x32x16_bf16(k1, qf[ds], st1, 0, 0, 0);
        }
        __builtin_amdgcn_s_setprio(0);

        short8 v00 = rfrag(KV[cb][1], l31, 0 + hi);
        short8 v10 = rfrag(KV[cb][1], 32 + l31, 0 + hi);
        short8 v01 = rfrag(KV[cb][1], l31, 2 + hi);
        short8 v11 = rfrag(KV[cb][1], 32 + l31, 2 + hi);

#pragma unroll
        for (int i = 0; i < 16; ++i) st0[i] = fexp2(st0[i]);
        short8 paf0 = pack8(st0, 0);
        short8 paf1 = pack8(st0, 8);

        __builtin_amdgcn_s_setprio(1);
        ot0 = __builtin_amdgcn_mfma_f32_32x32x16_bf16(v00, paf0, ot0, 0, 0, 0);
        ot1 = __builtin_amdgcn_mfma_f32_32x32x16_bf16(v10, paf0, ot1, 0, 0, 0);
        ot0 = __builtin_amdgcn_mfma_f32_32x32x16_bf16(v01, paf1, ot0, 0, 0, 0);
        ot1 = __builtin_amdgcn_mfma_f32_32x32x16_bf16(v11, paf1, ot1, 0, 0, 0);
        __builtin_amdgcn_s_setprio(0);

        short8 v02 = rfrag(KV[cb][1], l31, 4 + hi);
        short8 v12 = rfrag(KV[cb][1], 32 + l31, 4 + hi);
        short8 v03 = rfrag(KV[cb][1], l31, 6 + hi);
        short8 v13 = rfrag(KV[cb][1], 32 + l31, 6 + hi);
#pragma unroll
        for (int i = 0; i < 16; ++i) st1[i] = fexp2(st1[i]);
        short8 paf2 = pack8(st1, 0);
        short8 paf3 = pack8(st1, 8);

        __builtin_amdgcn_s_setprio(1);
        ot0 = __builtin_amdgcn_mfma_f32_32x32x16_bf16(v02, paf2, ot0, 0, 0, 0);
        ot1 = __builtin_amdgcn_mfma_f32_32x32x16_bf16(v12, paf2, ot1, 0, 0, 0);
        ot0 = __builtin_amdgcn_mfma_f32_32x32x16_bf16(v03, paf3, ot0, 0, 0, 0);
        ot1 = __builtin_amdgcn_mfma_f32_32x32x16_bf16(v13, paf3, ot1, 0, 0, 0);
        __builtin_amdgcn_s_setprio(0);

        float su[8];
#pragma unroll
        for (int i = 0; i < 8; ++i)
            su[i] = (st0[2 * i] + st0[2 * i + 1]) + (st1[2 * i] + st1[2 * i + 1]);
#pragma unroll
        for (int s = 4; s > 0; s >>= 1)
#pragma unroll
            for (int i = 0; i < 4; ++i)
                if (i < s) su[i] += su[i + s];
        l += su[0];

        cb = (cb == 2) ? 0 : cb + 1;
        sb = (sb == 2) ? 0 : sb + 1;
    }

    {
        unsigned int pu = __float_as_uint(l), pv = pu;
        pl32swap(pu, pv);
        l += __uint_as_float(hi ? pv : pu);
    }

    float inv = 1.f / l;
#pragma unroll
    for (int i = 0; i < 16; ++i) { ot0[i] *= inv; ot1[i] *= inv; }

    BARR();

    unsigned int* ow = (unsigned int*)(&KV[0][0][0]) + wave * 1152;  // 32x36, per-wave
#pragma unroll
    for (int dt = 0; dt < 2; ++dt)
#pragma unroll
        for (int rp = 0; rp < 8; ++rp) {
            unsigned int w = (dt == 0) ? cvtpk(ot0[2 * rp], ot0[2 * rp + 1])
                                       : cvtpk(ot1[2 * rp], ot1[2 * rp + 1]);
            int wd = dt * 16 + 4 * (rp >> 1) + 2 * hi + (rp & 1);
            ow[l31 * 36 + wd] = w;
        }
#pragma unroll
    for (int i = 0; i < 4; ++i) {
        int c = i * 64 + lane;
        int qr = c >> 3, ch = c & 7;
        short8 vv = *(const short8*)((const unsigned short*)&ow[qr * 36 + ch * 4]);
        *(short8*)&Og[(size_t)(b * 1024 + q0 + qr) * 768 + h * 64 + ch * 8] = vv;
    }
}

extern "C" void kernel_launch(void* const* d_in, const int* in_sizes, int n_in,
                              void* d_out, int out_size, void* d_ws, size_t ws_size,
                              hipStream_t stream) {
    const float* x      = (const float*)d_in[0];
    const float* w_qkv  = (const float*)d_in[1];
    const float* w_proj = (const float*)d_in[2];
    const float* b_proj = (const float*)d_in[3];
    float* out = (float*)d_out;

    const int Bb = 8, Nn = 1024, C = 768;
    const int M = Bb * Nn;                    // 8192
    const size_t WQ = (size_t)3 * C * C;
    const size_t WP = (size_t)C * C;
    const size_t QE = (size_t)96 * 1024 * 64;

    unsigned short* wqb = (unsigned short*)d_ws;
    unsigned short* wpb = wqb + WQ;
    unsigned short* Qb  = wpb + WP;
    unsigned short* Kb  = Qb + QE;
    unsigned short* Vtb = Kb + QE;
    unsigned short* AO  = Vtb + QE;

    // weights only: (WQ + WP)/4 = 589824 quads = 2304 blocks
    cvt_w<<<2304, 256, 0, stream>>>(w_qkv, w_proj, wqb, wpb);

    qkv_gemm<<<dim3(M / BM, (3 * C) / BN), 256, 0, stream>>>(
        x, wqb, Qb, Kb, Vtb);

    attn_kernel<<<768, 256, 0, stream>>>(Qb, Kb, Vtb, AO);

    proj_gemm<<<dim3(M / BM, C / BN), 256, 0, stream>>>(
        AO, wpb, out, b_proj, M, C, C);
}

// Round 18
// 109.491 us; speedup vs baseline: 1.5888x; 1.5888x over previous
//
#include <hip/hip_runtime.h>
#include <hip/hip_bf16.h>
#include <stdint.h>

typedef __attribute__((ext_vector_type(8))) short short8;
typedef __attribute__((ext_vector_type(4))) float f32x4;
typedef __attribute__((ext_vector_type(16))) float f32x16;
typedef __attribute__((ext_vector_type(4))) unsigned short us4;

#define AS1 __attribute__((address_space(1)))
#define AS3 __attribute__((address_space(3)))

__device__ inline unsigned short f2bf(float f) {
    unsigned int u = __float_as_uint(f);
    u += 0x7FFFu + ((u >> 16) & 1u);
    return (unsigned short)(u >> 16);
}

__device__ inline unsigned int cvtpk(float lo, float hi) {
    unsigned int r;
    asm("v_cvt_pk_bf16_f32 %0, %1, %2" : "=v"(r) : "v"(lo), "v"(hi));
    return r;
}

__device__ inline void pl32swap(unsigned int& a, unsigned int& b) {
    asm volatile("v_permlane32_swap_b32 %0, %1" : "+v"(a), "+v"(b));
}

__device__ inline float fexp2(float x) {
#if __has_builtin(__builtin_amdgcn_exp2f)
    return __builtin_amdgcn_exp2f(x);
#else
    return exp2f(x);
#endif
}

#define VMW(N) asm volatile("s_waitcnt vmcnt(" #N ")" ::: "memory")
#define BARR() __builtin_amdgcn_s_barrier()

// ---------------- fused fp32 -> bf16 conversion for x, w_qkv, w_proj --------
__global__ void cvt_all(const float* __restrict__ x, const float* __restrict__ wq,
                        const float* __restrict__ wp,
                        unsigned short* __restrict__ xb,
                        unsigned short* __restrict__ wqb,
                        unsigned short* __restrict__ wpb) {
    const int X4 = 1572864, Q4 = 442368;   // quads: XB/4, WQ/4 (WP/4 = 147456)
    int i = blockIdx.x * blockDim.x + threadIdx.x;
    const float* src; unsigned short* dst; int j;
    if (i < X4) { src = x; dst = xb; j = i; }
    else if (i < X4 + Q4) { src = wq; dst = wqb; j = i - X4; }
    else { src = wp; dst = wpb; j = i - X4 - Q4; }
    float4 v = ((const float4*)src)[j];
    us4 o;
    o.x = f2bf(v.x); o.y = f2bf(v.y); o.z = f2bf(v.z); o.w = f2bf(v.w);
    ((us4*)dst)[j] = o;
}

// ---------------- GEMM C = A * B^T  (A: MxK bf16, B: NxK bf16) ----------------
// 128x128 tile, BK=64 (12 iterations at K=768). 2-buffer counted-vmcnt:
// stage(it+1) -> vmcnt(8) (tile it landed, it+1's 8 loads stay in flight) ->
// barrier -> reads+MFMA -> barrier. LDS chunk-XOR swizzle (cd at cd^(r&7)).
// MODE 0: QKV proj -> Q/K [B*H,N,D] bf16 (Q scaled 0.125*log2e), V transposed
//         into Vt [B*H, D, N] with k-quad permutation (PV MFMA B-frag order).
// MODE 1: out projection -> fp32 C += bias
#define BM 128
#define BN 128

template<int MODE>
__global__ __launch_bounds__(256)
void gemm_bt(const unsigned short* __restrict__ A,
             const unsigned short* __restrict__ Bm,
             unsigned short* __restrict__ Qo, unsigned short* __restrict__ Ko,
             unsigned short* __restrict__ Vto,
             float* __restrict__ Co, const float* __restrict__ bias,
             int M, int N, int K)
{
    __shared__ __align__(16) unsigned short As[2][BM * 64];
    __shared__ __align__(16) unsigned short Bs[2][BM * 64];
    const int tid = threadIdx.x;
    const int wave = tid >> 6, lane = tid & 63;
    const int tr = blockIdx.x * BM;
    const int tc = blockIdx.y * BN;
    const int wm = wave >> 1, wn = wave & 1;

    f32x4 acc[4][4] = {};

    auto stage = [&](int it, int buf) {
#pragma unroll
        for (int i = 0; i < 4; ++i) {
            int cid = i * 256 + tid;          // 0..1023 = r*8 + cd
            int r = cid >> 3, cd = cid & 7;
            int sc = cd ^ (r & 7);            // pre-swizzled source chunk
            __builtin_amdgcn_global_load_lds(
                (const AS1 void*)(A + (size_t)(tr + r) * K + it * 64 + sc * 8),
                (AS3 void*)(&As[buf][(i * 256 + wave * 64) * 8]), 16, 0, 0);
            __builtin_amdgcn_global_load_lds(
                (const AS1 void*)(Bm + (size_t)(tc + r) * K + it * 64 + sc * 8),
                (AS3 void*)(&Bs[buf][(i * 256 + wave * 64) * 8]), 16, 0, 0);
        }
    };

    const int nIt = K / 64;                    // 12
    stage(0, 0);

    for (int it = 0; it < nIt; ++it) {
        const int cur = it & 1;
        if (it + 1 < nIt) { stage(it + 1, cur ^ 1); VMW(8); }
        else              { VMW(0); }
        BARR();                                // buf cur visible to all waves

#pragma unroll
        for (int kh = 0; kh < 2; ++kh) {
            short8 af[4], bfr[4];
#pragma unroll
            for (int mt = 0; mt < 4; ++mt) {
                int rr = wm * 64 + mt * 16 + (lane & 15);
                int c = kh * 4 + (lane >> 4);
                af[mt] = *(const short8*)&As[cur][rr * 64 + ((c ^ (rr & 7)) * 8)];
            }
#pragma unroll
            for (int nt = 0; nt < 4; ++nt) {
                int rr = wn * 64 + nt * 16 + (lane & 15);
                int c = kh * 4 + (lane >> 4);
                bfr[nt] = *(const short8*)&Bs[cur][rr * 64 + ((c ^ (rr & 7)) * 8)];
            }
#pragma unroll
            for (int mt = 0; mt < 4; ++mt)
#pragma unroll
                for (int nt = 0; nt < 4; ++nt)
                    acc[mt][nt] = __builtin_amdgcn_mfma_f32_16x16x32_bf16(af[mt], bfr[nt], acc[mt][nt], 0, 0, 0);
        }

        BARR();                                // reads done before next overwrite
    }

    const float QSCALE = 0.18033688011112042f;  // 0.125 * log2(e)
#pragma unroll
    for (int mt = 0; mt < 4; ++mt) {
#pragma unroll
        for (int nt = 0; nt < 4; ++nt) {
            int col = tc + wn * 64 + nt * 16 + (lane & 15);
            int row0 = tr + wm * 64 + mt * 16 + (lane >> 4) * 4;
            if constexpr (MODE == 0) {
                int s = (col >= 1536) ? 2 : (col >= 768 ? 1 : 0);
                int rem = col - s * 768;
                int h = rem >> 6, d = rem & 63;
                int b = row0 >> 10, n0 = row0 & 1023;
                int bh = b * 12 + h;
                if (s == 2) {
                    us4 pv;
#pragma unroll
                    for (int r = 0; r < 4; ++r) pv[r] = f2bf(acc[mt][nt][r]);
                    // k-quad permutation within each 16-group: [0-3][8-11][4-7][12-15]
                    int qd = (n0 >> 2) & 3;
                    int nst = n0 + ((qd == 1) ? 4 : (qd == 2) ? -4 : 0);
                    *(us4*)&Vto[((size_t)bh * 64 + d) * 1024 + nst] = pv;
                } else {
                    unsigned short* dst = (s == 0) ? Qo : Ko;
                    float sc = (s == 0) ? QSCALE : 1.0f;
#pragma unroll
                    for (int r = 0; r < 4; ++r)
                        dst[((size_t)bh * 1024 + n0 + r) * 64 + d] = f2bf(acc[mt][nt][r] * sc);
                }
            } else {
#pragma unroll
                for (int r = 0; r < 4; ++r)
                    Co[(size_t)(row0 + r) * N + col] = acc[mt][nt][r] + bias[col];
            }
        }
    }
}

// ---------------- flash attention (32x32 swapped QK^T, static softmax) ------
// 1D grid 768 = 96 bh x 8 q-blocks, XCD-chunked by head (K/V L2-local).
// 3-deep ring, ONE barrier/iter.
__global__ __launch_bounds__(256, 3)
void attn_kernel(const unsigned short* __restrict__ Q,
                 const unsigned short* __restrict__ Kg,
                 const unsigned short* __restrict__ Vt,
                 unsigned short* __restrict__ Og)
{
    __shared__ __align__(16) unsigned short KV[3][2][64 * 64];

    const int tid = threadIdx.x;
    const int wave = tid >> 6, lane = tid & 63;
    const int l31 = lane & 31, hi = lane >> 5;

    const int id = blockIdx.x;                 // 768 blocks
    const int swz = (id & 7) * 96 + (id >> 3);
    const int bh = swz >> 3, qb = swz & 7;

    const int b = bh / 12, h = bh % 12;
    const size_t baseK = (size_t)bh * 1024 * 64;
    const size_t baseV = (size_t)bh * 64 * 1024;
    const int q0 = qb * 128 + wave * 32;

    short8 qf[4];
#pragma unroll
    for (int ds = 0; ds < 4; ++ds)
        qf[ds] = *(const short8*)&Q[baseK + (size_t)(q0 + l31) * 64 + ds * 16 + hi * 8];

    f32x16 ot0 = {}, ot1 = {};
    float l = 0.f;

    auto stage = [&](int kt, int buf) {
        const unsigned short* gK = Kg + baseK + (size_t)kt * 64 * 64;
        const unsigned short* gV = Vt + baseV + kt * 64;
#pragma unroll
        for (int i = 0; i < 2; ++i) {
            int c = wave * 128 + i * 64 + lane;
            int r = c >> 3, cc = c & 7;
            int sw = (cc ^ (r & 7)) * 8;
            __builtin_amdgcn_global_load_lds(
                (const AS1 void*)(gK + r * 64 + sw),
                (AS3 void*)(&KV[buf][0][(wave * 128 + i * 64) * 8]), 16, 0, 0);
            __builtin_amdgcn_global_load_lds(
                (const AS1 void*)(gV + (size_t)r * 1024 + sw),
                (AS3 void*)(&KV[buf][1][(wave * 128 + i * 64) * 8]), 16, 0, 0);
        }
    };

    auto rfrag = [&](const unsigned short* s, int row, int cc) -> short8 {
        return *(const short8*)&s[(row * 8 + (cc ^ (row & 7))) * 8];
    };

    auto pack8 = [&](const f32x16& S, int r0) -> short8 {
        union { unsigned int u[4]; short8 s; } fr;
#pragma unroll
        for (int w = 0; w < 4; ++w)
            fr.u[w] = cvtpk(S[r0 + 2 * w], S[r0 + 2 * w + 1]);
        return fr.s;
    };

    stage(0, 0);
    stage(1, 1);
    int cb = 0, sb = 2;

    for (int kt = 0; kt < 16; ++kt) {
        if (kt < 15) { VMW(4); }
        else         { VMW(0); }
        BARR();                                // everyone done reading kt-1; kt ready
        if (kt < 14) stage(kt + 2, sb);        // overwrites buffer of kt-1 (safe)

        f32x16 st0 = {}, st1 = {};
        __builtin_amdgcn_s_setprio(1);
#pragma unroll
        for (int ds = 0; ds < 4; ++ds) {
            short8 k0 = rfrag(KV[cb][0], l31, ds * 2 + hi);
            short8 k1 = rfrag(KV[cb][0], 32 + l31, ds * 2 + hi);
            st0 = __builtin_amdgcn_mfma_f32_32x32x16_bf16(k0, qf[ds], st0, 0, 0, 0);
            st1 = __builtin_amdgcn_mfma_f32_32x32x16_bf16(k1, qf[ds], st1, 0, 0, 0);
        }
        __builtin_amdgcn_s_setprio(0);

        short8 v00 = rfrag(KV[cb][1], l31, 0 + hi);
        short8 v10 = rfrag(KV[cb][1], 32 + l31, 0 + hi);
        short8 v01 = rfrag(KV[cb][1], l31, 2 + hi);
        short8 v11 = rfrag(KV[cb][1], 32 + l31, 2 + hi);

#pragma unroll
        for (int i = 0; i < 16; ++i) st0[i] = fexp2(st0[i]);
        short8 paf0 = pack8(st0, 0);
        short8 paf1 = pack8(st0, 8);

        __builtin_amdgcn_s_setprio(1);
        ot0 = __builtin_amdgcn_mfma_f32_32x32x16_bf16(v00, paf0, ot0, 0, 0, 0);
        ot1 = __builtin_amdgcn_mfma_f32_32x32x16_bf16(v10, paf0, ot1, 0, 0, 0);
        ot0 = __builtin_amdgcn_mfma_f32_32x32x16_bf16(v01, paf1, ot0, 0, 0, 0);
        ot1 = __builtin_amdgcn_mfma_f32_32x32x16_bf16(v11, paf1, ot1, 0, 0, 0);
        __builtin_amdgcn_s_setprio(0);

        short8 v02 = rfrag(KV[cb][1], l31, 4 + hi);
        short8 v12 = rfrag(KV[cb][1], 32 + l31, 4 + hi);
        short8 v03 = rfrag(KV[cb][1], l31, 6 + hi);
        short8 v13 = rfrag(KV[cb][1], 32 + l31, 6 + hi);
#pragma unroll
        for (int i = 0; i < 16; ++i) st1[i] = fexp2(st1[i]);
        short8 paf2 = pack8(st1, 0);
        short8 paf3 = pack8(st1, 8);

        __builtin_amdgcn_s_setprio(1);
        ot0 = __builtin_amdgcn_mfma_f32_32x32x16_bf16(v02, paf2, ot0, 0, 0, 0);
        ot1 = __builtin_amdgcn_mfma_f32_32x32x16_bf16(v12, paf2, ot1, 0, 0, 0);
        ot0 = __builtin_amdgcn_mfma_f32_32x32x16_bf16(v03, paf3, ot0, 0, 0, 0);
        ot1 = __builtin_amdgcn_mfma_f32_32x32x16_bf16(v13, paf3, ot1, 0, 0, 0);
        __builtin_amdgcn_s_setprio(0);

        float su[8];
#pragma unroll
        for (int i = 0; i < 8; ++i)
            su[i] = (st0[2 * i] + st0[2 * i + 1]) + (st1[2 * i] + st1[2 * i + 1]);
#pragma unroll
        for (int s = 4; s > 0; s >>= 1)
#pragma unroll
            for (int i = 0; i < 4; ++i)
                if (i < s) su[i] += su[i + s];
        l += su[0];

        cb = (cb == 2) ? 0 : cb + 1;
        sb = (sb == 2) ? 0 : sb + 1;
    }

    {
        unsigned int pu = __float_as_uint(l), pv = pu;
        pl32swap(pu, pv);
        l += __uint_as_float(hi ? pv : pu);
    }

    float inv = 1.f / l;
#pragma unroll
    for (int i = 0; i < 16; ++i) { ot0[i] *= inv; ot1[i] *= inv; }

    // make sure all waves finished their last-tile LDS reads before reuse
    BARR();

    unsigned int* ow = (unsigned int*)(&KV[0][0][0]) + wave * 1152;  // 32x36, per-wave
#pragma unroll
    for (int dt = 0; dt < 2; ++dt)
#pragma unroll
        for (int rp = 0; rp < 8; ++rp) {
            unsigned int w = (dt == 0) ? cvtpk(ot0[2 * rp], ot0[2 * rp + 1])
                                       : cvtpk(ot1[2 * rp], ot1[2 * rp + 1]);
            int wd = dt * 16 + 4 * (rp >> 1) + 2 * hi + (rp & 1);
            ow[l31 * 36 + wd] = w;
        }
#pragma unroll
    for (int i = 0; i < 4; ++i) {
        int c = i * 64 + lane;
        int qr = c >> 3, ch = c & 7;
        short8 vv = *(const short8*)((const unsigned short*)&ow[qr * 36 + ch * 4]);
        *(short8*)&Og[(size_t)(b * 1024 + q0 + qr) * 768 + h * 64 + ch * 8] = vv;
    }
}

extern "C" void kernel_launch(void* const* d_in, const int* in_sizes, int n_in,
                              void* d_out, int out_size, void* d_ws, size_t ws_size,
                              hipStream_t stream) {
    const float* x      = (const float*)d_in[0];
    const float* w_qkv  = (const float*)d_in[1];
    const float* w_proj = (const float*)d_in[2];
    const float* b_proj = (const float*)d_in[3];
    float* out = (float*)d_out;

    const int Bb = 8, Nn = 1024, C = 768;
    const int M = Bb * Nn;                    // 8192
    const size_t XB = (size_t)M * C;
    const size_t WQ = (size_t)3 * C * C;
    const size_t WP = (size_t)C * C;
    const size_t QE = (size_t)96 * 1024 * 64;

    unsigned short* xb  = (unsigned short*)d_ws;
    unsigned short* wqb = xb + XB;
    unsigned short* wpb = wqb + WQ;
    unsigned short* Qb  = wpb + WP;
    unsigned short* Kb  = Qb + QE;
    unsigned short* Vtb = Kb + QE;
    unsigned short* AO  = Vtb + QE;

    cvt_all<<<8448, 256, 0, stream>>>(x, w_qkv, w_proj, xb, wqb, wpb);

    gemm_bt<0><<<dim3(M / BM, (3 * C) / BN), 256, 0, stream>>>(
        xb, wqb, Qb, Kb, Vtb, nullptr, nullptr, M, 3 * C, C);

    attn_kernel<<<768, 256, 0, stream>>>(Qb, Kb, Vtb, AO);

    gemm_bt<1><<<dim3(M / BM, C / BN), 256, 0, stream>>>(
        AO, wpb, nullptr, nullptr, nullptr, out, b_proj, M, C, C);
}